// Round 4
// baseline (322.942 us; speedup 1.0000x reference)
//
#include <hip/hip_runtime.h>

// Spiking basal ganglia: T=512 sequential LIF steps, B=256 circuits.
// One wave per batch; lane i owns d1 neurons {2i,2i+1} and d2 {2i,2i+1}.
// STN/GPI populations get uniform input -> one scalar each. Means are exact
// popcounts/128 (ballot). Math is bit-identical to the R2/R3 passing kernels
// (contract off, fma-contracted K=2 dots).
//
// R3 post-mortem: 1 wave/SIMD + LDS round-trip left ~240 cyc/step of exposed
// ds_read latency (VALUBusy 12%). This version prefetches straight into
// REGISTERS, depth 8. R2's scratch demotion (VGPR_Count=40) was caused by the
// conditional tail prefetch; here the prefetch index is clamped (min(t+8,511))
// so every pipeline slot is unconditionally assigned -> SROA keeps it in VGPRs.
// Per-step lane-0 stores are replaced by a gate latch (1 cndmask/step) and one
// coalesced-issue store per 64-step window, keeping vmcnt clean for prefetch.

__global__ __launch_bounds__(64) void bg_kernel(
    const float* __restrict__ x,      // [T,B,2]
    const float* __restrict__ dopa,   // [T,B]
    const float* __restrict__ Wd1,    // [128,2]
    const float* __restrict__ Wd2,    // [128,2]
    const float* __restrict__ nd1,    // [T,B,128]
    const float* __restrict__ nd2,    // [T,B,128]
    float* __restrict__ out)          // [T,B]
{
#pragma clang fp contract(off)
    constexpr int T = 512, B = 256;
    constexpr int D = 8;    // register prefetch depth
    constexpr int W = 64;   // steps per window (gate latch width)

    const int b    = blockIdx.x;
    const int lane = threadIdx.x;

    const float4 w1 = *(const float4*)(Wd1 + 4 * lane);
    const float4 w2 = *(const float4*)(Wd2 + 4 * lane);

    const float* n1base = nd1 + (size_t)b * 128 + 2 * lane;
    const float* n2base = nd2 + (size_t)b * 128 + 2 * lane;
    const float* xbase  = x + (size_t)b * 2;
    const float* dbase  = dopa + b;
    constexpr size_t NSTRIDE = (size_t)B * 128;
    constexpr size_t XSTRIDE = (size_t)B * 2;

    // ---- register prefetch pipeline, depth D (unconditional -> SROA-safe) ----
    float2 p1[D], p2[D], px[D];
    float  pd[D];
#pragma unroll
    for (int d = 0; d < D; ++d) {
        p1[d] = *(const float2*)(n1base + (size_t)d * NSTRIDE);
        p2[d] = *(const float2*)(n2base + (size_t)d * NSTRIDE);
        px[d] = *(const float2*)(xbase + (size_t)d * XSTRIDE);
        pd[d] = dbase[(size_t)d * B];
    }

    float v1a = 0.0f, v1b = 0.0f;
    float v2a = 0.0f, v2b = 0.0f;
    float v_stn = 0.0f, v_gpi = 0.0f;

    for (int w = 0; w < T / W; ++w) {       // 8 windows, not unrolled
        float gate_reg = 0.0f;              // lane L latches gate of step w*64+L

#pragma unroll
        for (int s = 0; s < W; ++s) {
            const int t = w * W + s;
            const int slot = s & (D - 1);   // static per unrolled body

            const float2 n1 = p1[slot];
            const float2 n2 = p2[slot];
            const float2 xv = px[slot];
            const float  dop = pd[slot];

            // Unconditional clamped prefetch (refetching t=511 at the tail is
            // harmless; keeps every slot assigned on every path).
            int tp = t + D;
            tp = (tp < T) ? tp : (T - 1);
            p1[slot] = *(const float2*)(n1base + (size_t)tp * NSTRIDE);
            p2[slot] = *(const float2*)(n2base + (size_t)tp * NSTRIDE);
            px[slot] = *(const float2*)(xbase + (size_t)tp * XSTRIDE);
            pd[slot] = dbase[(size_t)tp * B];

            // ---- bit-identical math to the R2/R3 passing kernels ----
            const float m1 = 1.0f + dop * 0.5f;
            const float m2 = 1.0f - dop * 0.3f;

            const float dot1a = __builtin_fmaf(xv.y, w1.y, xv.x * w1.x);
            const float dot1b = __builtin_fmaf(xv.y, w1.w, xv.x * w1.z);
            const float dot2a = __builtin_fmaf(xv.y, w2.y, xv.x * w2.x);
            const float dot2b = __builtin_fmaf(xv.y, w2.w, xv.x * w2.z);

            float Ia = dot1a * m1 + n1.x * 0.1f;
            float Ib = dot1b * m1 + n1.y * 0.1f;
            float Ja = dot2a * m2 + n2.x * 0.1f;
            float Jb = dot2b * m2 + n2.y * 0.1f;

            v1a = 0.8f * v1a + 0.2f * Ia;
            v1b = 0.8f * v1b + 0.2f * Ib;
            v2a = 0.8f * v2a + 0.2f * Ja;
            v2b = 0.8f * v2b + 0.2f * Jb;

            const bool s1a = v1a >= 0.5f, s1b = v1b >= 0.5f;
            const bool s2a = v2a >= 0.5f, s2b = v2b >= 0.5f;
            v1a = s1a ? 0.0f : v1a;
            v1b = s1b ? 0.0f : v1b;
            v2a = s2a ? 0.0f : v2a;
            v2b = s2b ? 0.0f : v2b;

            const int c1 = __popcll(__ballot(s1a)) + __popcll(__ballot(s1b));
            const int c2 = __popcll(__ballot(s2a)) + __popcll(__ballot(s2b));
            const float mean1 = (float)c1 * 0.0078125f;
            const float mean2 = (float)c2 * 0.0078125f;

            const float I_stn = mean2 * 0.5f;
            v_stn = 0.8f * v_stn + 0.2f * I_stn;
            const float s_stn = (v_stn >= 0.5f) ? 1.0f : 0.0f;
            v_stn = (v_stn >= 0.5f) ? 0.0f : v_stn;

            const float I_gpi = (0.4f + mean1 * -0.8f) + s_stn * 0.6f;
            v_gpi = 0.8f * v_gpi + 0.2f * I_gpi;
            const float s_gpi = (v_gpi >= 0.5f) ? 1.0f : 0.0f;
            v_gpi = (v_gpi >= 0.5f) ? 0.0f : v_gpi;

            const float gate = mean1 - s_gpi;   // wave-uniform

            // Lane s latches this step's gate (1 cndmask; s is a literal).
            gate_reg = (lane == s) ? gate : gate_reg;
        }

        // One store per window: lane L writes gate of step w*64+L.
        out[(size_t)(w * W + lane) * B + b] = gate_reg;
    }
}

extern "C" void kernel_launch(void* const* d_in, const int* in_sizes, int n_in,
                              void* d_out, int out_size, void* d_ws, size_t ws_size,
                              hipStream_t stream) {
    const float* x    = (const float*)d_in[0];
    const float* dopa = (const float*)d_in[1];
    // d_in[2] = rpe — unused by the reference
    const float* Wd1  = (const float*)d_in[3];
    const float* Wd2  = (const float*)d_in[4];
    const float* nd1  = (const float*)d_in[5];
    const float* nd2  = (const float*)d_in[6];
    float* out = (float*)d_out;

    bg_kernel<<<dim3(256), dim3(64), 0, stream>>>(x, dopa, Wd1, Wd2, nd1, nd2, out);
}